// Round 7
// baseline (252.091 us; speedup 1.0000x reference)
//
#include <hip/hip_runtime.h>
#include <cstdint>
#include <cstddef>

// ---------------------------------------------------------------------------
// StyleDownBlock: styles -> demod -> (blur4x4 ∘ conv3x3 stride2 grouped) -> lrelu
// N=16, I=256, O=512, H=W=64, out 16x512x32x32 fp32.
// R7: conv A-operand (bf16 weights, 2.36MB, L2-resident) loaded DIRECTLY from
//   global into VGPR fragments (dbuf) — LDS staging/barrier only for B; LDS
//   reads halve, A-side VALU gone. Blur: 8-row groups (refetch 2x -> 1.375x).
// ---------------------------------------------------------------------------

typedef short bf16x8 __attribute__((ext_vector_type(8)));
typedef float f32x4  __attribute__((ext_vector_type(4)));

#define CGSTR 4460544   // per-cg stride in xfp: 16n * 4planes * 33*33 * 64ch
#define NSTR  278784    // per-n stride within cg: 4 * 1089 * 64
#define PLSTR 69696     // per-plane stride: 1089 * 64

__device__ __forceinline__ unsigned short f2bf(float f) {
  union { float f; unsigned u; } v; v.f = f;
  unsigned r = (v.u + 0x7FFFu + ((v.u >> 16) & 1u)) >> 16;  // RNE
  return (unsigned short)r;
}

__device__ __forceinline__ void gload_lds16(const void* g, void* l) {
  __builtin_amdgcn_global_load_lds((const __attribute__((address_space(1))) void*)g,
                                   (__attribute__((address_space(3))) void*)l,
                                   16, 0, 0);
}

// ---- stage 1: styles[n,i] = dot(w[n,:], affine_w[i,:])/sqrt(512) + affine_b[i]
__global__ void styles_kernel(const float* __restrict__ w, const float* __restrict__ aw,
                              const float* __restrict__ ab, float* __restrict__ styles) {
  const int n = blockIdx.x;      // 16
  const int i = threadIdx.x;     // 256
  const float4* wr = (const float4*)(w + (size_t)n * 512);
  const float4* ar = (const float4*)(aw + (size_t)i * 512);
  float acc = 0.f;
#pragma unroll 4
  for (int k = 0; k < 128; ++k) {
    float4 a = wr[k], c = ar[k];
    acc += a.x * c.x + a.y * c.y + a.z * c.z + a.w * c.w;
  }
  styles[n * 256 + i] = acc * 0.04419417382415922f + ab[i];  // 1/sqrt(512)
}

// ---- stage 2: one pass over weight: wsq[o,i] AND flipped bf16 wtb[tap][o][i]
__global__ void wtcvt_kernel(const float* __restrict__ wt, unsigned short* __restrict__ wtb,
                             float* __restrict__ wsq) {
  const int o = blockIdx.x;      // 512
  const int i = threadIdx.x;     // 256
  const float* p = wt + ((size_t)o * 256 + i) * 9;
  float v[9];
  float s = 0.f;
#pragma unroll
  for (int k = 0; k < 9; ++k) { v[k] = p[k]; s += v[k] * v[k]; }
  wsq[o * 256 + i] = s;
#pragma unroll
  for (int tap = 0; tap < 9; ++tap)
    wtb[((size_t)tap * 512 + o) * 256 + i] = f2bf(v[8 - tap]);
}

// ---- stage 3: dcoefs[n,o] = rsqrt(sum_i wsq[o,i]*styles[n,i]^2 + 1e-8)
__global__ void dcoefs_kernel(const float* __restrict__ wsq, const float* __restrict__ styles,
                              float* __restrict__ dcoefs) {
  __shared__ float st2[256];
  const int n = blockIdx.x;      // 16
  const int t = threadIdx.x;     // 512
  if (t < 256) { float s = styles[n * 256 + t]; st2[t] = s * s; }
  __syncthreads();
  const float4* wr = (const float4*)(wsq + (size_t)t * 256);
  const float4* sr = (const float4*)st2;
  float acc = 0.f;
#pragma unroll 4
  for (int k = 0; k < 64; ++k) {
    float4 a = wr[k], c = sr[k];
    acc += a.x * c.x + a.y * c.y + a.z * c.z + a.w * c.w;
  }
  dcoefs[n * 512 + t] = 1.0f / sqrtf(acc + 1e-8f);
}

// ---- stage 4: separable 4x4 blur of (styles ⊙ x), pad 2, bf16 out,
// layout xfp[cg][n][ph][pw][r(33)][c(33)][64ch].
// Grid (R7): 16n x 8rg(8 rows, last 9) x 4cg = 512 blocks, 256 thr.
// Vertical+horizontal in registers (shfl strip exchange); bf16 -> dbuf LDS pad
// -> cooperative channel-major 16B stores.
__global__ __launch_bounds__(256, 4) void blur_kernel(const float* __restrict__ x,
                                                      const float* __restrict__ styles,
                                                      unsigned short* __restrict__ xfp) {
  __shared__ unsigned short shls[2][64][68];
  const int b = blockIdx.x;
  const int n = b >> 5;
  const int rem = b & 31;
  const int rg = rem >> 2;              // 0..7
  const int cg = rem & 3;
  const int tid = threadIdx.x;
  const int ch = tid >> 2;              // 0..63 local channel
  const int s4 = tid & 3;               // col strip
  const int col0 = s4 * 16;
  const float* xin = x + ((size_t)(n * 256 + cg * 64 + ch) << 12);
  const float sv = styles[n * 256 + cg * 64 + ch];
  const float F0s = 0.125f * sv, F1s = 0.375f * sv;   // styles folded in
  const float F0 = 0.125f, F1 = 0.375f;
  const int ybase = rg * 8;
  const int ylim = (rg == 7) ? 9 : 8;
  const size_t obase = (size_t)(cg * 16 + n) * 4 * PLSTR;

  float4 rA[4], rB[4], rC[4], rD[4], rN[4];
  auto load4 = [&](int row, float4* dst) {
    if ((unsigned)row < 64u) {
      const float4* p = (const float4*)(xin + row * 64 + col0);
      dst[0] = p[0]; dst[1] = p[1]; dst[2] = p[2]; dst[3] = p[3];
    } else {
      const float4 z = {0.f, 0.f, 0.f, 0.f};
      dst[0] = z; dst[1] = z; dst[2] = z; dst[3] = z;
    }
  };
  load4(ybase - 2, rA); load4(ybase - 1, rB); load4(ybase, rC); load4(ybase + 1, rD);

#pragma unroll 1
  for (int yy = 0; yy < ylim; ++yy) {
    const int y = ybase + yy;           // 0..64
    load4(y + 2, rN);                   // prefetch next row
    // vertical filter (styles folded) -> ve[2..17] = cols col0..col0+15;
    // ve[0..1] from left neighbor, ve[18] from right, ve[19] = zero pad
    float ve[20];
#pragma unroll
    for (int q = 0; q < 4; ++q) {
      ve[2 + q * 4 + 0] = F0s * rA[q].x + F1s * rB[q].x + F1s * rC[q].x + F0s * rD[q].x;
      ve[2 + q * 4 + 1] = F0s * rA[q].y + F1s * rB[q].y + F1s * rC[q].y + F0s * rD[q].y;
      ve[2 + q * 4 + 2] = F0s * rA[q].z + F1s * rB[q].z + F1s * rC[q].z + F0s * rD[q].z;
      ve[2 + q * 4 + 3] = F0s * rA[q].w + F1s * rB[q].w + F1s * rC[q].w + F0s * rD[q].w;
    }
    float vm2 = __shfl_up(ve[16], 1);   // left strip's col0-2
    float vm1 = __shfl_up(ve[17], 1);   // left strip's col0-1
    float vp1 = __shfl_down(ve[2], 1);  // right strip's col0+16
    if (s4 == 0) { vm2 = 0.f; vm1 = 0.f; }
    if (s4 == 3) vp1 = 0.f;
    ve[0] = vm2; ve[1] = vm1; ve[18] = vp1; ve[19] = 0.f;
    unsigned short hv[17];
#pragma unroll
    for (int pl = 0; pl < 17; ++pl)
      hv[pl] = f2bf(F0 * ve[pl] + F1 * ve[pl + 1] + F1 * ve[pl + 2] + F0 * ve[pl + 3]);
    unsigned short (*sh)[68] = shls[yy & 1];
    unsigned* dst32 = (unsigned*)&sh[ch][col0];
#pragma unroll
    for (int q = 0; q < 8; ++q)
      dst32[q] = (unsigned)hv[2 * q] | ((unsigned)hv[2 * q + 1] << 16);
    if (s4 == 3) sh[ch][64] = hv[16];   // p=64 (pw=0, c=32)
    __syncthreads();
    // cooperative channel-major store: 65 positions x 8 chunks of 8ch
    const int ph = y & 1, r = y >> 1;
#pragma unroll 1
    for (int sI = tid; sI < 520; sI += 256) {
      const int p = sI >> 3, j = sI & 7;
      union { bf16x8 vv; unsigned short u[8]; } pk;
#pragma unroll
      for (int k = 0; k < 8; ++k) pk.u[k] = sh[j * 8 + k][p];
      const int pw = p & 1, cc = p >> 1;
      const size_t off = obase + (size_t)(ph * 2 + pw) * PLSTR + (r * 33 + cc) * 64 + j * 8;
      *(bf16x8*)(xfp + off) = pk.vv;
    }
#pragma unroll
    for (int q = 0; q < 4; ++q) { rA[q] = rB[q]; rB[q] = rC[q]; rC[q] = rD[q]; rD[q] = rN[q]; }
  }
}

// ---- stage 5 (R7): implicit GEMM conv. A = bf16 weights read DIRECTLY from
// global (L2-resident 2.36MB) into dbuf VGPR frags; LDS staging only for B.
// grid 512: idx = om*128 + pt*16 + n -> XCD = n%8 (B-tile L2 locality).
// 128(M=o) x 128(N=pos) tile, K = 72 x 32 (9 taps x 8 kb).
__global__ __launch_bounds__(256) void conv_kernel(
    const unsigned short* __restrict__ wtb,
    const unsigned short* __restrict__ xfp,
    const float* __restrict__ dcoefs,
    const float* __restrict__ bias,
    float* __restrict__ out) {
  __shared__ unsigned short Bs0[4096], Bs1[4096];  // 8KB each
  const int idx = blockIdx.x;
  const int om = idx >> 7;        // 0..3
  const int g = idx & 127;
  const int pt = g >> 4;          // 0..7
  const int n = g & 15;           // XCD = idx%8 = n%8
  const int o0 = om << 7;
  const int oh0 = pt << 2;
  const int tid = threadIdx.x;
  const int lane = tid & 63;
  const int wv = tid >> 6;
  const int wm = wv >> 1;
  const int wp = wv & 1;
  const int ml = lane & 15;
  const int kq = lane >> 4;

  f32x4 acc[4][4];
  const f32x4 zz = {0.f, 0.f, 0.f, 0.f};
#pragma unroll
  for (int i = 0; i < 4; ++i)
#pragma unroll
    for (int j = 0; j < 4; ++j) acc[i][j] = zz;

  // B staging slots (as before)
  const int s0 = wv * 128 + lane, s1 = s0 + 64;
  const int r0 = s0 >> 2, g0 = (s0 & 3) * 8;
  const int r1 = s1 >> 2, g1 = (s1 & 3) * 8;
  const int row0 = oh0 + (r0 >> 5), col0 = r0 & 31;
  const int row1 = oh0 + (r1 >> 5), col1 = r1 & 31;
  const size_t nB = (size_t)n * NSTR;

  // A fragment lane pointers (tap/kb-invariant part)
  const unsigned short* aptr[4];
#pragma unroll
  for (int t = 0; t < 4; ++t)
    aptr[t] = wtb + (size_t)(o0 + wm * 64 + t * 16 + ml) * 256 + kq * 8;

  auto stageB = [&](int kt, unsigned short* Bs) {
    const int tap = kt >> 3, kb = kt & 7;
    const int kh = (tap * 11) >> 5;           // tap/3
    const int kw = tap - kh * 3;
    const int ph = kh & 1, dr = kh >> 1;
    const int pw = kw & 1, dc = kw >> 1;
    const unsigned short* Bt = xfp + (size_t)(kb >> 1) * CGSTR + nB +
                               (size_t)(ph * 2 + pw) * PLSTR + (kb & 1) * 32;
    gload_lds16(Bt + ((row0 + dr) * 33 + col0 + dc) * 64 + g0, Bs + wv * 1024);
    gload_lds16(Bt + ((row1 + dr) * 33 + col1 + dc) * 64 + g1, Bs + wv * 1024 + 512);
  };
  auto loadA = [&](int kt, bf16x8* af) {
    const int tap = kt >> 3, kb = kt & 7;
    const int koff = tap * 131072 + kb * 32;
#pragma unroll
    for (int t = 0; t < 4; ++t) af[t] = *(const bf16x8*)(aptr[t] + koff);
  };
  auto compute = [&](const bf16x8* af, const unsigned short* Bs) {
    bf16x8 bfv[4];
    const bf16x8* B8 = (const bf16x8*)Bs;
#pragma unroll
    for (int t = 0; t < 4; ++t)
      bfv[t] = B8[(wp * 64 + t * 16 + ml) * 4 + kq];
#pragma unroll
    for (int mt = 0; mt < 4; ++mt)
#pragma unroll
      for (int nt = 0; nt < 4; ++nt)
        acc[mt][nt] = __builtin_amdgcn_mfma_f32_16x16x32_bf16(af[mt], bfv[nt], acc[mt][nt], 0, 0, 0);
  };

  bf16x8 afA[4], afB[4];
  stageB(0, Bs0);
  loadA(0, afA);
#pragma unroll 1
  for (int kt = 0; kt < 72; kt += 2) {
    __syncthreads();                    // B tile kt resident in Bs0
    stageB(kt + 1, Bs1);                // prefetch next B
    loadA(kt + 1, afB);                 // prefetch next A (VGPR)
    compute(afA, Bs0);
    __syncthreads();                    // B tile kt+1 resident in Bs1
    if (kt + 2 < 72) { stageB(kt + 2, Bs0); loadA(kt + 2, afA); }
    compute(afB, Bs1);
  }

  // epilogue: C/D layout col=lane&15 (pos), row=(lane>>4)*4+reg (o).
  // v = acc*dcoef + bias -> lrelu*sqrt2.
  f32x4 dc4[4], bi4[4];
#pragma unroll
  for (int mt = 0; mt < 4; ++mt) {
    const int ob = o0 + wm * 64 + mt * 16 + kq * 4;
    dc4[mt] = *(const f32x4*)(dcoefs + n * 512 + ob);
    bi4[mt] = *(const f32x4*)(bias + ob);
  }
#pragma unroll
  for (int mt = 0; mt < 4; ++mt) {
#pragma unroll
    for (int nt = 0; nt < 4; ++nt) {
      const int p = wp * 64 + nt * 16 + ml;
      const int oh = oh0 + (p >> 5), ow = p & 31;
#pragma unroll
      for (int r = 0; r < 4; ++r) {
        const int o = o0 + wm * 64 + mt * 16 + kq * 4 + r;
        float v = acc[mt][nt][r] * dc4[mt][r] + bi4[mt][r];
        v = (v >= 0.f ? v : 0.2f * v) * 1.41421356237309515f;
        out[(((size_t)n * 512 + o) * 32 + oh) * 32 + ow] = v;
      }
    }
  }
}

extern "C" void kernel_launch(void* const* d_in, const int* in_sizes, int n_in,
                              void* d_out, int out_size, void* d_ws, size_t ws_size,
                              hipStream_t stream) {
  const float* x  = (const float*)d_in[0];   // [16,256,64,64]
  const float* w  = (const float*)d_in[1];   // [16,512]
  const float* aw = (const float*)d_in[2];   // [256,512]
  const float* ab = (const float*)d_in[3];   // [256]
  const float* wt = (const float*)d_in[4];   // [512,256,3,3]
  const float* bs = (const float*)d_in[5];   // [512]
  float* out = (float*)d_out;                // [16,512,32,32]

  char* ws = (char*)d_ws;
  float* styles        = (float*)(ws);                       // 16 KB
  float* dcoefs        = (float*)(ws + 16384);               // 32 KB
  float* wsq           = (float*)(ws + 49152);               // 512 KB
  unsigned short* wtb  = (unsigned short*)(ws + 573440);     // 2.36 MB
  unsigned short* xfp  = (unsigned short*)(ws + 2932736);    // 35.68 MB  (total ~38.6 MB)

  styles_kernel<<<dim3(16),   dim3(256), 0, stream>>>(w, aw, ab, styles);
  wtcvt_kernel <<<dim3(512),  dim3(256), 0, stream>>>(wt, wtb, wsq);
  dcoefs_kernel<<<dim3(16),   dim3(512), 0, stream>>>(wsq, styles, dcoefs);
  blur_kernel  <<<dim3(512),  dim3(256), 0, stream>>>(x, styles, xfp);
  conv_kernel  <<<dim3(512),  dim3(256), 0, stream>>>(wtb, xfp, dcoefs, bs, out);
}

// Round 8
// 197.084 us; speedup vs baseline: 1.2791x; 1.2791x over previous
//
#include <hip/hip_runtime.h>
#include <cstdint>
#include <cstddef>

// ---------------------------------------------------------------------------
// StyleDownBlock: styles -> demod -> (blur4x4 ∘ conv3x3 stride2 grouped) -> lrelu
// N=16, I=256, O=512, H=W=64, out 16x512x32x32 fp32.
// R8: revert R7's direct-global A (scattered 512B-stride loads, 60->101us).
// Conv K-loop restructured: BK=64 (36 barriers, was 72), XOR-swizzled LDS
// granules (b128 reads at 4-way floor, was 8-way), hoisted per-lane staging
// offsets (uniform base + const per stage). A+B both LDS-staged as in R6.
// ---------------------------------------------------------------------------

typedef short bf16x8 __attribute__((ext_vector_type(8)));
typedef float f32x4  __attribute__((ext_vector_type(4)));

#define CGSTR 4460544   // per-cg stride in xfp: 16n * 4planes * 33*33 * 64ch
#define NSTR  278784    // per-n stride within cg: 4 * 1089 * 64
#define PLSTR 69696     // per-plane stride: 1089 * 64

__device__ __forceinline__ unsigned short f2bf(float f) {
  union { float f; unsigned u; } v; v.f = f;
  unsigned r = (v.u + 0x7FFFu + ((v.u >> 16) & 1u)) >> 16;  // RNE
  return (unsigned short)r;
}

__device__ __forceinline__ void gload_lds16(const void* g, void* l) {
  __builtin_amdgcn_global_load_lds((const __attribute__((address_space(1))) void*)g,
                                   (__attribute__((address_space(3))) void*)l,
                                   16, 0, 0);
}

// ---- stage 1: styles[n,i] = dot(w[n,:], affine_w[i,:])/sqrt(512) + affine_b[i]
__global__ void styles_kernel(const float* __restrict__ w, const float* __restrict__ aw,
                              const float* __restrict__ ab, float* __restrict__ styles) {
  const int n = blockIdx.x;      // 16
  const int i = threadIdx.x;     // 256
  const float4* wr = (const float4*)(w + (size_t)n * 512);
  const float4* ar = (const float4*)(aw + (size_t)i * 512);
  float acc = 0.f;
#pragma unroll 4
  for (int k = 0; k < 128; ++k) {
    float4 a = wr[k], c = ar[k];
    acc += a.x * c.x + a.y * c.y + a.z * c.z + a.w * c.w;
  }
  styles[n * 256 + i] = acc * 0.04419417382415922f + ab[i];  // 1/sqrt(512)
}

// ---- stage 2: one pass over weight: wsq[o,i] AND flipped bf16 wtb[tap][o][i]
__global__ void wtcvt_kernel(const float* __restrict__ wt, unsigned short* __restrict__ wtb,
                             float* __restrict__ wsq) {
  const int o = blockIdx.x;      // 512
  const int i = threadIdx.x;     // 256
  const float* p = wt + ((size_t)o * 256 + i) * 9;
  float v[9];
  float s = 0.f;
#pragma unroll
  for (int k = 0; k < 9; ++k) { v[k] = p[k]; s += v[k] * v[k]; }
  wsq[o * 256 + i] = s;
#pragma unroll
  for (int tap = 0; tap < 9; ++tap)
    wtb[((size_t)tap * 512 + o) * 256 + i] = f2bf(v[8 - tap]);
}

// ---- stage 3: dcoefs[n,o] = rsqrt(sum_i wsq[o,i]*styles[n,i]^2 + 1e-8)
__global__ void dcoefs_kernel(const float* __restrict__ wsq, const float* __restrict__ styles,
                              float* __restrict__ dcoefs) {
  __shared__ float st2[256];
  const int n = blockIdx.x;      // 16
  const int t = threadIdx.x;     // 512
  if (t < 256) { float s = styles[n * 256 + t]; st2[t] = s * s; }
  __syncthreads();
  const float4* wr = (const float4*)(wsq + (size_t)t * 256);
  const float4* sr = (const float4*)st2;
  float acc = 0.f;
#pragma unroll 4
  for (int k = 0; k < 64; ++k) {
    float4 a = wr[k], c = sr[k];
    acc += a.x * c.x + a.y * c.y + a.z * c.z + a.w * c.w;
  }
  dcoefs[n * 512 + t] = 1.0f / sqrtf(acc + 1e-8f);
}

// ---- stage 4: separable 4x4 blur of (styles ⊙ x), pad 2, bf16 out,
// layout xfp[cg][n][ph][pw][r(33)][c(33)][64ch].
// Grid: 16n x 8rg(8 rows, last 9) x 4cg = 512 blocks, 256 thr.
__global__ __launch_bounds__(256, 4) void blur_kernel(const float* __restrict__ x,
                                                      const float* __restrict__ styles,
                                                      unsigned short* __restrict__ xfp) {
  __shared__ unsigned short shls[2][64][68];
  const int b = blockIdx.x;
  const int n = b >> 5;
  const int rem = b & 31;
  const int rg = rem >> 2;              // 0..7
  const int cg = rem & 3;
  const int tid = threadIdx.x;
  const int ch = tid >> 2;              // 0..63 local channel
  const int s4 = tid & 3;               // col strip
  const int col0 = s4 * 16;
  const float* xin = x + ((size_t)(n * 256 + cg * 64 + ch) << 12);
  const float sv = styles[n * 256 + cg * 64 + ch];
  const float F0s = 0.125f * sv, F1s = 0.375f * sv;   // styles folded in
  const float F0 = 0.125f, F1 = 0.375f;
  const int ybase = rg * 8;
  const int ylim = (rg == 7) ? 9 : 8;
  const size_t obase = (size_t)(cg * 16 + n) * 4 * PLSTR;

  float4 rA[4], rB[4], rC[4], rD[4], rN[4];
  auto load4 = [&](int row, float4* dst) {
    if ((unsigned)row < 64u) {
      const float4* p = (const float4*)(xin + row * 64 + col0);
      dst[0] = p[0]; dst[1] = p[1]; dst[2] = p[2]; dst[3] = p[3];
    } else {
      const float4 z = {0.f, 0.f, 0.f, 0.f};
      dst[0] = z; dst[1] = z; dst[2] = z; dst[3] = z;
    }
  };
  load4(ybase - 2, rA); load4(ybase - 1, rB); load4(ybase, rC); load4(ybase + 1, rD);

#pragma unroll 1
  for (int yy = 0; yy < ylim; ++yy) {
    const int y = ybase + yy;           // 0..64
    load4(y + 2, rN);                   // prefetch next row
    float ve[20];
#pragma unroll
    for (int q = 0; q < 4; ++q) {
      ve[2 + q * 4 + 0] = F0s * rA[q].x + F1s * rB[q].x + F1s * rC[q].x + F0s * rD[q].x;
      ve[2 + q * 4 + 1] = F0s * rA[q].y + F1s * rB[q].y + F1s * rC[q].y + F0s * rD[q].y;
      ve[2 + q * 4 + 2] = F0s * rA[q].z + F1s * rB[q].z + F1s * rC[q].z + F0s * rD[q].z;
      ve[2 + q * 4 + 3] = F0s * rA[q].w + F1s * rB[q].w + F1s * rC[q].w + F0s * rD[q].w;
    }
    float vm2 = __shfl_up(ve[16], 1);   // left strip's col0-2
    float vm1 = __shfl_up(ve[17], 1);   // left strip's col0-1
    float vp1 = __shfl_down(ve[2], 1);  // right strip's col0+16
    if (s4 == 0) { vm2 = 0.f; vm1 = 0.f; }
    if (s4 == 3) vp1 = 0.f;
    ve[0] = vm2; ve[1] = vm1; ve[18] = vp1; ve[19] = 0.f;
    unsigned short hv[17];
#pragma unroll
    for (int pl = 0; pl < 17; ++pl)
      hv[pl] = f2bf(F0 * ve[pl] + F1 * ve[pl + 1] + F1 * ve[pl + 2] + F0 * ve[pl + 3]);
    unsigned short (*sh)[68] = shls[yy & 1];
    unsigned* dst32 = (unsigned*)&sh[ch][col0];
#pragma unroll
    for (int q = 0; q < 8; ++q)
      dst32[q] = (unsigned)hv[2 * q] | ((unsigned)hv[2 * q + 1] << 16);
    if (s4 == 3) sh[ch][64] = hv[16];   // p=64 (pw=0, c=32)
    __syncthreads();
    const int ph = y & 1, r = y >> 1;
#pragma unroll 1
    for (int sI = tid; sI < 520; sI += 256) {
      const int p = sI >> 3, j = sI & 7;
      union { bf16x8 vv; unsigned short u[8]; } pk;
#pragma unroll
      for (int k = 0; k < 8; ++k) pk.u[k] = sh[j * 8 + k][p];
      const int pw = p & 1, cc = p >> 1;
      const size_t off = obase + (size_t)(ph * 2 + pw) * PLSTR + (r * 33 + cc) * 64 + j * 8;
      *(bf16x8*)(xfp + off) = pk.vv;
    }
#pragma unroll
    for (int q = 0; q < 4; ++q) { rA[q] = rB[q]; rB[q] = rC[q]; rC[q] = rD[q]; rD[q] = rN[q]; }
  }
}

// ---- stage 5 (R8): implicit GEMM conv, BK=64, XOR-swizzled LDS, dbuf.
// grid 512: idx = om*128 + pt*16 + n -> XCD = n%8 (B-tile L2 locality).
// 128(M=o) x 128(N=pos) tile, K = 36 tiles of 64 (9 taps x 4 cg-pairs).
// LDS granule (16B) layout: phys = row*8 + (go ^ (row&7)); staging applies the
// swizzle on the GLOBAL k-offset so global_load_lds dest stays lane-linear.
__global__ __launch_bounds__(256) void conv_kernel(
    const unsigned short* __restrict__ wtb,
    const unsigned short* __restrict__ xfp,
    const float* __restrict__ dcoefs,
    const float* __restrict__ bias,
    float* __restrict__ out) {
  __shared__ unsigned short As0[8192], Bs0[8192];  // 16KB each
  __shared__ unsigned short As1[8192], Bs1[8192];  // total 64KB
  const int idx = blockIdx.x;
  const int om = idx >> 7;        // 0..3
  const int g = idx & 127;
  const int pt = g >> 4;          // 0..7
  const int n = g & 15;           // XCD = idx%8 = n%8
  const int o0 = om << 7;
  const int oh0 = pt << 2;
  const int tid = threadIdx.x;
  const int lane = tid & 63;
  const int wv = tid >> 6;
  const int wm = wv >> 1;
  const int wp = wv & 1;
  const int ml = lane & 15;
  const int kq = lane >> 4;

  f32x4 acc[4][4];
  const f32x4 zz = {0.f, 0.f, 0.f, 0.f};
#pragma unroll
  for (int i = 0; i < 4; ++i)
#pragma unroll
    for (int j = 0; j < 4; ++j) acc[i][j] = zz;

  // --- staging geometry: wave wv covers granules [wv*256, wv*256+256), 4 per lane
  const int rowbase = wv * 32 + (lane >> 3);                 // row of slot j=0
  const int glog8 = (((lane & 7) ^ ((lane >> 3) & 7))) * 8;  // swizzled k-offset (shorts)
  int aoffj[4], boffj[4];
#pragma unroll
  for (int j = 0; j < 4; ++j) {
    const int r = rowbase + j * 8;
    aoffj[j] = (o0 + r) * 256 + glog8;
    boffj[j] = ((oh0 + (r >> 5)) * 33 + (r & 31)) * 64 + glog8;
  }
  const size_t nB = (size_t)n * NSTR;
  // --- read-side swizzled granule indices (per lane, per K-half)
  const int gi0 = (0 * 4 + kq) ^ (ml & 7);
  const int gi1 = (1 * 4 + kq) ^ (ml & 7);

  auto stage = [&](int kt, unsigned short* As, unsigned short* Bs) {
    const int tap = kt >> 2, pair = kt & 3;
    const int kh = (tap * 11) >> 5;           // tap/3
    const int kw = tap - kh * 3;
    const int ph = kh & 1, dr = kh >> 1;
    const int pw = kw & 1, dc = kw >> 1;
    const unsigned short* At = wtb + tap * 131072 + pair * 64;
    const unsigned short* Bt = xfp + (size_t)pair * CGSTR + nB +
                               (size_t)(ph * 2 + pw) * PLSTR + (dr * 33 + dc) * 64;
#pragma unroll
    for (int j = 0; j < 4; ++j) {
      gload_lds16(At + aoffj[j], As + (wv * 256 + j * 64) * 8);
      gload_lds16(Bt + boffj[j], Bs + (wv * 256 + j * 64) * 8);
    }
  };
  auto compute = [&](const unsigned short* As, const unsigned short* Bs) {
    const bf16x8* A8 = (const bf16x8*)As;
    const bf16x8* B8 = (const bf16x8*)Bs;
#pragma unroll
    for (int h = 0; h < 2; ++h) {
      const int gi = h ? gi1 : gi0;
      bf16x8 af[4], bfv[4];
#pragma unroll
      for (int t = 0; t < 4; ++t) {
        af[t]  = A8[(wm * 64 + t * 16 + ml) * 8 + gi];
        bfv[t] = B8[(wp * 64 + t * 16 + ml) * 8 + gi];
      }
#pragma unroll
      for (int mt = 0; mt < 4; ++mt)
#pragma unroll
        for (int nt = 0; nt < 4; ++nt)
          acc[mt][nt] = __builtin_amdgcn_mfma_f32_16x16x32_bf16(af[mt], bfv[nt], acc[mt][nt], 0, 0, 0);
    }
  };

  stage(0, As0, Bs0);
#pragma unroll 1
  for (int kt = 0; kt < 36; kt += 2) {
    __syncthreads();                    // tile kt resident in buf0
    stage(kt + 1, As1, Bs1);            // prefetch overlaps compute
    compute(As0, Bs0);
    __syncthreads();                    // tile kt+1 resident in buf1
    if (kt + 2 < 36) stage(kt + 2, As0, Bs0);
    compute(As1, Bs1);
  }

  // epilogue: C/D layout col=lane&15 (pos), row=(lane>>4)*4+reg (o).
  // v = acc*dcoef + bias -> lrelu*sqrt2.
  f32x4 dc4[4], bi4[4];
#pragma unroll
  for (int mt = 0; mt < 4; ++mt) {
    const int ob = o0 + wm * 64 + mt * 16 + kq * 4;
    dc4[mt] = *(const f32x4*)(dcoefs + n * 512 + ob);
    bi4[mt] = *(const f32x4*)(bias + ob);
  }
#pragma unroll
  for (int mt = 0; mt < 4; ++mt) {
#pragma unroll
    for (int nt = 0; nt < 4; ++nt) {
      const int p = wp * 64 + nt * 16 + ml;
      const int oh = oh0 + (p >> 5), ow = p & 31;
#pragma unroll
      for (int r = 0; r < 4; ++r) {
        const int o = o0 + wm * 64 + mt * 16 + kq * 4 + r;
        float v = acc[mt][nt][r] * dc4[mt][r] + bi4[mt][r];
        v = (v >= 0.f ? v : 0.2f * v) * 1.41421356237309515f;
        out[(((size_t)n * 512 + o) * 32 + oh) * 32 + ow] = v;
      }
    }
  }
}

extern "C" void kernel_launch(void* const* d_in, const int* in_sizes, int n_in,
                              void* d_out, int out_size, void* d_ws, size_t ws_size,
                              hipStream_t stream) {
  const float* x  = (const float*)d_in[0];   // [16,256,64,64]
  const float* w  = (const float*)d_in[1];   // [16,512]
  const float* aw = (const float*)d_in[2];   // [256,512]
  const float* ab = (const float*)d_in[3];   // [256]
  const float* wt = (const float*)d_in[4];   // [512,256,3,3]
  const float* bs = (const float*)d_in[5];   // [512]
  float* out = (float*)d_out;                // [16,512,32,32]

  char* ws = (char*)d_ws;
  float* styles        = (float*)(ws);                       // 16 KB
  float* dcoefs        = (float*)(ws + 16384);               // 32 KB
  float* wsq           = (float*)(ws + 49152);               // 512 KB
  unsigned short* wtb  = (unsigned short*)(ws + 573440);     // 2.36 MB
  unsigned short* xfp  = (unsigned short*)(ws + 2932736);    // 35.68 MB  (total ~38.6 MB)

  styles_kernel<<<dim3(16),   dim3(256), 0, stream>>>(w, aw, ab, styles);
  wtcvt_kernel <<<dim3(512),  dim3(256), 0, stream>>>(wt, wtb, wsq);
  dcoefs_kernel<<<dim3(16),   dim3(512), 0, stream>>>(wsq, styles, dcoefs);
  blur_kernel  <<<dim3(512),  dim3(256), 0, stream>>>(x, styles, xfp);
  conv_kernel  <<<dim3(512),  dim3(256), 0, stream>>>(wtb, xfp, dcoefs, bs, out);
}